// Round 2
// baseline (1279.673 us; speedup 1.0000x reference)
//
#include <hip/hip_runtime.h>
#include <cstddef>

// Problem constants (fixed by reference setup_inputs)
#define H_      92
#define W_      124
#define N_      (H_ * W_)      // 11408
#define C_      256
#define K_      4
#define SR_     4
#define WIN_    9
#define LEVELS_ 5

#define TILE_   64
#define KC_     16
#define NT_     ((N_ + TILE_ - 1) / TILE_)   // 179 n-tiles
#define NEG_INF_ (-1.0e30f)

// ---------------------------------------------------------------------------
// Kernel A: fused scores-GEMM + running top-4 per row over an m-range.
// scores[n,m] = sum_c f1[c*N+n] * f2[c*N+m]   (fp32 exact)
// Grid: (179 n-tiles, SPLITS m-splits). Each block scans its m-range in
// 64-wide tiles, wave 0 maintains a running top-4 (val,idx) per row.
// Strict > with ascending m == jax.lax.top_k tie-break (lower idx first).
// ---------------------------------------------------------------------------
__global__ __launch_bounds__(256)
void knn_partial_kernel(const float* __restrict__ f1, const float* __restrict__ f2,
                        float* __restrict__ pval, int* __restrict__ pidx,
                        int mt_per_split)
{
    __shared__ float As[KC_][TILE_];
    __shared__ float Bs[KC_][TILE_];
    __shared__ float Ss[TILE_][TILE_ + 1];   // +1 pad: scan is conflict-free

    const int nb    = blockIdx.x;
    const int split = blockIdx.y;
    const int n0    = nb * TILE_;
    const int tid   = threadIdx.x;
    const int tx    = tid & 15;          // m micro-tile
    const int ty    = tid >> 4;          // n micro-tile
    const int lr    = tid >> 4;          // staging: row 0..15
    const int lc    = (tid & 15) * 4;    // staging: col (float4)

    const bool edge_n = (n0 + TILE_ > N_);

    float rv0 = NEG_INF_, rv1 = NEG_INF_, rv2 = NEG_INF_, rv3 = NEG_INF_;
    int   ri0 = 0, ri1 = 0, ri2 = 0, ri3 = 0;

    const int mtiles   = NT_;
    const int mt_begin = split * mt_per_split;
    const int mt_end   = (mt_begin + mt_per_split < mtiles) ? (mt_begin + mt_per_split) : mtiles;

    for (int mt = mt_begin; mt < mt_end; ++mt) {
        const int  m0     = mt * TILE_;
        const bool edge_m = (m0 + TILE_ > N_);

        float acc[4][4];
        #pragma unroll
        for (int i = 0; i < 4; ++i)
            #pragma unroll
            for (int j = 0; j < 4; ++j)
                acc[i][j] = 0.0f;

        for (int kc = 0; kc < C_; kc += KC_) {
            __syncthreads();   // protect As/Bs of previous chunk
            const float* a_src = f1 + (size_t)(kc + lr) * N_;
            const float* b_src = f2 + (size_t)(kc + lr) * N_;
            if (!edge_n) {
                *(float4*)&As[lr][lc] = *(const float4*)(a_src + n0 + lc);
            } else {
                #pragma unroll
                for (int i = 0; i < 4; ++i) {
                    int n = n0 + lc + i; if (n > N_ - 1) n = N_ - 1;
                    As[lr][lc + i] = a_src[n];
                }
            }
            if (!edge_m) {
                *(float4*)&Bs[lr][lc] = *(const float4*)(b_src + m0 + lc);
            } else {
                #pragma unroll
                for (int i = 0; i < 4; ++i) {
                    int m = m0 + lc + i; if (m > N_ - 1) m = N_ - 1;
                    Bs[lr][lc + i] = b_src[m];
                }
            }
            __syncthreads();

            #pragma unroll
            for (int k = 0; k < KC_; ++k) {
                const float4 a = *(const float4*)&As[k][ty * 4];
                const float4 b = *(const float4*)&Bs[k][tx * 4];
                acc[0][0] = fmaf(a.x, b.x, acc[0][0]);
                acc[0][1] = fmaf(a.x, b.y, acc[0][1]);
                acc[0][2] = fmaf(a.x, b.z, acc[0][2]);
                acc[0][3] = fmaf(a.x, b.w, acc[0][3]);
                acc[1][0] = fmaf(a.y, b.x, acc[1][0]);
                acc[1][1] = fmaf(a.y, b.y, acc[1][1]);
                acc[1][2] = fmaf(a.y, b.z, acc[1][2]);
                acc[1][3] = fmaf(a.y, b.w, acc[1][3]);
                acc[2][0] = fmaf(a.z, b.x, acc[2][0]);
                acc[2][1] = fmaf(a.z, b.y, acc[2][1]);
                acc[2][2] = fmaf(a.z, b.z, acc[2][2]);
                acc[2][3] = fmaf(a.z, b.w, acc[2][3]);
                acc[3][0] = fmaf(a.w, b.x, acc[3][0]);
                acc[3][1] = fmaf(a.w, b.y, acc[3][1]);
                acc[3][2] = fmaf(a.w, b.z, acc[3][2]);
                acc[3][3] = fmaf(a.w, b.w, acc[3][3]);
            }
        }
        __syncthreads();
        // stage the 64x64 score tile
        #pragma unroll
        for (int i = 0; i < 4; ++i)
            #pragma unroll
            for (int j = 0; j < 4; ++j)
                Ss[ty * 4 + i][tx * 4 + j] = acc[i][j];
        __syncthreads();

        if (tid < TILE_) {
            const int mlim = edge_m ? (N_ - m0) : TILE_;
            for (int m = 0; m < mlim; ++m) {
                const float s = Ss[tid][m];
                if (s > rv3) {
                    const int mi = m0 + m;
                    if (s > rv1) {
                        if (s > rv0) {
                            rv3 = rv2; ri3 = ri2; rv2 = rv1; ri2 = ri1;
                            rv1 = rv0; ri1 = ri0; rv0 = s;   ri0 = mi;
                        } else {
                            rv3 = rv2; ri3 = ri2; rv2 = rv1; ri2 = ri1;
                            rv1 = s;   ri1 = mi;
                        }
                    } else {
                        if (s > rv2) { rv3 = rv2; ri3 = ri2; rv2 = s; ri2 = mi; }
                        else         { rv3 = s;   ri3 = mi; }
                    }
                }
            }
        }
        __syncthreads();
    }

    if (tid < TILE_) {
        const int n = n0 + tid;
        if (n < N_) {
            const size_t base = ((size_t)split * N_ + n) * 4;
            pval[base + 0] = rv0; pidx[base + 0] = ri0;
            pval[base + 1] = rv1; pidx[base + 1] = ri1;
            pval[base + 2] = rv2; pidx[base + 2] = ri2;
            pval[base + 3] = rv3; pidx[base + 3] = ri3;
        }
    }
}

// ---------------------------------------------------------------------------
// Kernel B: merge split top-4 lists -> exact top-4, then the 5-level bilinear
// scatter into the dense [405][N] cost volume. One thread per pixel; each
// pixel owns its 405 channels (no races). corr = score / sqrt(256).
// ---------------------------------------------------------------------------
__global__ __launch_bounds__(256)
void scatter_kernel(const float* __restrict__ pval, const int* __restrict__ pidx,
                    const float* __restrict__ dflow, float* __restrict__ out,
                    int splits)
{
    const int n = blockIdx.x * blockDim.x + threadIdx.x;
    if (n >= N_) return;

    float v[4]  = {NEG_INF_, NEG_INF_, NEG_INF_, NEG_INF_};
    int   id[4] = {0, 0, 0, 0};

    for (int s = 0; s < splits; ++s) {
        const size_t base = ((size_t)s * N_ + n) * 4;
        #pragma unroll
        for (int k = 0; k < 4; ++k) {
            const float sv = pval[base + k];
            const int   si = pidx[base + k];
            // total order: value desc, idx asc on ties (matches lax.top_k)
            if ((sv > v[3]) || (sv == v[3] && si < id[3])) {
                if ((sv > v[1]) || (sv == v[1] && si < id[1])) {
                    if ((sv > v[0]) || (sv == v[0] && si < id[0])) {
                        v[3] = v[2]; id[3] = id[2]; v[2] = v[1]; id[2] = id[1];
                        v[1] = v[0]; id[1] = id[0]; v[0] = sv;   id[0] = si;
                    } else {
                        v[3] = v[2]; id[3] = id[2]; v[2] = v[1]; id[2] = id[1];
                        v[1] = sv;   id[1] = si;
                    }
                } else if ((sv > v[2]) || (sv == v[2] && si < id[2])) {
                    v[3] = v[2]; id[3] = id[2]; v[2] = sv; id[2] = si;
                } else {
                    v[3] = sv; id[3] = si;
                }
            }
        }
    }

    const int   y0  = n / W_;
    const int   x0  = n - y0 * W_;
    const float df0 = dflow[n];        // delta_flow channel 0
    const float df1 = dflow[N_ + n];   // delta_flow channel 1
    // cc = disp(y,x) - delta_flow[(1,0)]  (reference reverses channels)
    float ccy[4], ccx[4], cr[4];
    #pragma unroll
    for (int k = 0; k < 4; ++k) {
        const int m  = id[k];
        const int y1 = m / W_;
        const int x1 = m - y1 * W_;
        cr[k]  = v[k] * 0.0625f;                  // / sqrt(C)=16
        ccy[k] = (float)(y1 - y0) - df1;
        ccx[k] = (float)(x1 - x0) - df0;
    }

    float scale = 1.0f;
    for (int lvl = 0; lvl < LEVELS_; ++lvl) {
        float bins[WIN_ * WIN_];
        for (int j = 0; j < WIN_ * WIN_; ++j) bins[j] = 0.0f;

        #pragma unroll
        for (int k = 0; k < 4; ++k) {
            const float cy = ccy[k] * scale;
            const float cx = ccx[k] * scale;
            const float yf = floorf(cy), xf = floorf(cx);
            const float dy = cy - yf,    dx = cx - xf;
            const float w00 = (1.0f - dy) * (1.0f - dx);
            const float w01 = (1.0f - dy) * dx;
            const float w10 = dy * (1.0f - dx);
            const float w11 = dy * dx;
            const float cyv[4] = {yf, yf, yf + 1.0f, yf + 1.0f};
            const float cxv[4] = {xf, xf + 1.0f, xf, xf + 1.0f};
            const float wv[4]  = {w00, w01, w10, w11};
            #pragma unroll
            for (int c = 0; c < 4; ++c) {
                if (fabsf(cyv[c]) <= (float)SR_ && fabsf(cxv[c]) <= (float)SR_) {
                    const int iy = (int)cyv[c] + SR_;
                    const int ix = (int)cxv[c] + SR_;
                    bins[iy * WIN_ + ix] += wv[c] * cr[k];
                }
            }
        }

        const size_t obase = (size_t)lvl * (WIN_ * WIN_) * N_ + n;
        for (int j = 0; j < WIN_ * WIN_; ++j)
            out[obase + (size_t)j * N_] = bins[j];
        scale *= 0.5f;
    }
}

// ---------------------------------------------------------------------------
extern "C" void kernel_launch(void* const* d_in, const int* in_sizes, int n_in,
                              void* d_out, int out_size, void* d_ws, size_t ws_size,
                              hipStream_t stream)
{
    const float* f1    = (const float*)d_in[0];
    const float* f2    = (const float*)d_in[1];
    const float* dflow = (const float*)d_in[2];
    float*       out   = (float*)d_out;

    // workspace per split: N*4 floats (vals) + N*4 ints (idx) = 32*N bytes.
    // Degrade gracefully if the harness hands us a small workspace.
    const size_t per_split = (size_t)N_ * 32u;
    int splits = 1;
    while (splits < 8 && (size_t)(splits * 2) * per_split <= ws_size) splits *= 2;

    float* pval = (float*)d_ws;
    int*   pidx = (int*)((char*)d_ws + (size_t)splits * N_ * 4 * sizeof(float));

    const int mtiles = NT_;
    const int mps    = (mtiles + splits - 1) / splits;

    dim3 gridA(NT_, splits);
    knn_partial_kernel<<<gridA, 256, 0, stream>>>(f1, f2, pval, pidx, mps);

    const int nthreads = 256;
    const int nblocks  = (N_ + nthreads - 1) / nthreads;
    scatter_kernel<<<nblocks, nthreads, 0, stream>>>(pval, pidx, dflow, out, splits);
}

// Round 4
// 499.115 us; speedup vs baseline: 2.5639x; 2.5639x over previous
//
#include <hip/hip_runtime.h>
#include <cstddef>
#include <climits>

// Problem constants (fixed by reference setup_inputs)
#define H_      92
#define W_      124
#define N_      (H_ * W_)      // 11408
#define C_      256
#define SR_     4
#define WIN_    9
#define LEVELS_ 5
#define NEG_INF_ (-1.0e30f)

// ---- MFMA path geometry ----
#define BM_     128            // m per block-chunk
#define BN_     128            // n-stripe per block
#define BK_     32             // k-chunk
#define MT_     ((N_ + BM_ - 1) / BM_)   // 90 m-chunks
#define NTB_    ((N_ + BN_ - 1) / BN_)   // 90 n-blocks
#define SPL_    15             // m-splits (90 = 15*6)
#define MPS_    (MT_ / SPL_)   // 6 m-chunks per split

typedef __attribute__((ext_vector_type(8))) short bf16x8;
typedef __attribute__((ext_vector_type(4))) float f32x4;

#define AS1 __attribute__((address_space(1)))
#define AS3 __attribute__((address_space(3)))

__device__ __forceinline__ void gload16(const void* gp, void* lp) {
    __builtin_amdgcn_global_load_lds((const AS1 void*)gp, (AS3 void*)lp, 16, 0, 0);
}

__device__ __forceinline__ unsigned short f2bf(float x) {
    unsigned u = __float_as_uint(x);
    u = (u + 0x7fffu + ((u >> 16) & 1u)) >> 16;
    return (unsigned short)u;
}
__device__ __forceinline__ float bf2f(unsigned short h) {
    return __uint_as_float(((unsigned)h) << 16);
}

// sorted-desc top-4 insert, strict > (ascending-index scan => lowest idx on ties)
// slot conditions: p0: c1; p1: !c1&&c2; p2: !c2&&c3; p3: !c3.
__device__ __forceinline__ void ins4(float v, int m, float s[4], int ix[4]) {
    if (v > s[3]) {
        const bool c1 = v > s[0];
        const bool c2 = v > s[1];
        const bool c3 = v > s[2];
        const float n0 = c1 ? v : s[0];               const int m0_ = c1 ? m : ix[0];
        const float n1 = c1 ? s[0] : (c2 ? v : s[1]); const int m1 = c1 ? ix[0] : (c2 ? m : ix[1]);
        const float n2 = c2 ? s[1] : (c3 ? v : s[2]); const int m2 = c2 ? ix[1] : (c3 ? m : ix[2]);
        const float n3 = c3 ? s[2] : v;               const int m3 = c3 ? ix[2] : m;
        s[0] = n0; s[1] = n1; s[2] = n2; s[3] = n3;
        ix[0] = m0_; ix[1] = m1; ix[2] = m2; ix[3] = m3;
    }
}

// tie-breaking top-4 insert: order by (val desc, idx asc)
__device__ __forceinline__ void ins4tb(float v, int m, float s[4], int ix[4]) {
    const bool g3 = (v > s[3]) || (v == s[3] && m < ix[3]);
    if (g3) {
        const bool c1 = (v > s[0]) || (v == s[0] && m < ix[0]);
        const bool c2 = (v > s[1]) || (v == s[1] && m < ix[1]);
        const bool c3 = (v > s[2]) || (v == s[2] && m < ix[2]);
        const float n0 = c1 ? v : s[0];               const int m0_ = c1 ? m : ix[0];
        const float n1 = c1 ? s[0] : (c2 ? v : s[1]); const int m1 = c1 ? ix[0] : (c2 ? m : ix[1]);
        const float n2 = c2 ? s[1] : (c3 ? v : s[2]); const int m2 = c2 ? ix[1] : (c3 ? m : ix[2]);
        const float n3 = c3 ? s[2] : v;               const int m3 = c3 ? ix[2] : m;
        s[0] = n0; s[1] = n1; s[2] = n2; s[3] = n3;
        ix[0] = m0_; ix[1] = m1; ix[2] = m2; ix[3] = m3;
    }
}

// ---------------------------------------------------------------------------
// Kernel P: transpose + split-bf16 conversion.
//  z=0: f1 -> f1T fp32 [N][C], f1hi/f1lo bf16 [N][C]
//  z=1: f2 -> f2T fp32 [N][C], f2hi/f2lo bf16 [N][C]
// ---------------------------------------------------------------------------
__global__ __launch_bounds__(256)
void prep_kernel(const float* __restrict__ f1, const float* __restrict__ f2,
                 unsigned short* __restrict__ f1hi, unsigned short* __restrict__ f1lo,
                 unsigned short* __restrict__ f2hi, unsigned short* __restrict__ f2lo,
                 float* __restrict__ f1T, float* __restrict__ f2T)
{
    __shared__ float tile[64][65];
    const int c0 = blockIdx.x * 64;
    const int n0 = blockIdx.y * 64;
    const int z  = blockIdx.z;
    const float* src = z ? f2 : f1;
    unsigned short* thi = z ? f2hi : f1hi;
    unsigned short* tlo = z ? f2lo : f1lo;
    float* tT = z ? f2T : f1T;

    const int t  = threadIdx.x;
    const int r  = t >> 4;          // 0..15
    const int c4 = (t & 15) * 4;

    if (n0 + 64 <= N_) {
        #pragma unroll
        for (int i = 0; i < 4; ++i) {
            const int c = c0 + r + i * 16;
            const float4 v = *(const float4*)(src + (size_t)c * N_ + n0 + c4);
            tile[r + i*16][c4+0] = v.x; tile[r + i*16][c4+1] = v.y;
            tile[r + i*16][c4+2] = v.z; tile[r + i*16][c4+3] = v.w;
        }
    } else {
        #pragma unroll
        for (int i = 0; i < 4; ++i) {
            const int c = c0 + r + i * 16;
            for (int j = 0; j < 4; ++j) {
                int n = n0 + c4 + j; if (n > N_ - 1) n = N_ - 1;
                tile[r + i*16][c4 + j] = src[(size_t)c * N_ + n];
            }
        }
    }
    __syncthreads();

    #pragma unroll
    for (int i = 0; i < 4; ++i) {
        const int nl = r + i * 16;
        const int n  = n0 + nl;
        if (n < N_) {
            float x0 = tile[c4+0][nl], x1 = tile[c4+1][nl];
            float x2 = tile[c4+2][nl], x3 = tile[c4+3][nl];
            float4 fv; fv.x = x0; fv.y = x1; fv.z = x2; fv.w = x3;
            *(float4*)(tT + (size_t)n * C_ + c0 + c4) = fv;
            unsigned short h0 = f2bf(x0), h1 = f2bf(x1), h2 = f2bf(x2), h3 = f2bf(x3);
            ushort4 hv; hv.x = h0; hv.y = h1; hv.z = h2; hv.w = h3;
            *(ushort4*)(thi + (size_t)n * C_ + c0 + c4) = hv;
            ushort4 lv;
            lv.x = f2bf(x0 - bf2f(h0)); lv.y = f2bf(x1 - bf2f(h1));
            lv.z = f2bf(x2 - bf2f(h2)); lv.w = f2bf(x3 - bf2f(h3));
            *(ushort4*)(tlo + (size_t)n * C_ + c0 + c4) = lv;
        }
    }
}

// ---------------------------------------------------------------------------
// Kernel A (MFMA): split-bf16 scores + per-lane-partition top-4 candidates.
// Block: 256 thr (4 waves). n-stripe = 128 (wave w owns n-tiles 2w,2w+1).
// m scanned in 128-chunks over this split's range. D = A(f2) x B(f1):
// D row = m = (lane>>4)*4+reg within tile, col = n = lane&15.
// Wave w stages one plane: w0->f2hi, w1->f2lo, w2->f1hi, w3->f1lo.
// ---------------------------------------------------------------------------
__global__ __launch_bounds__(256)
void knn_mfma_kernel(const unsigned short* __restrict__ f1hi, const unsigned short* __restrict__ f1lo,
                     const unsigned short* __restrict__ f2hi, const unsigned short* __restrict__ f2lo,
                     float* __restrict__ pval, int* __restrict__ pidx)
{
    __shared__ __align__(16) char smem[32768];   // 4 planes x 8KB (staging) / merge reuse

    const int tid = threadIdx.x;
    const int w   = tid >> 6;
    const int l   = tid & 63;
    const int n0  = blockIdx.x * BN_;
    const int s   = blockIdx.y;

    // lane-partition top-4 state for the lane's two n's (j=0,1)
    float sv[2][4]; int sx[2][4];
    #pragma unroll
    for (int j = 0; j < 2; ++j) {
        #pragma unroll
        for (int q = 0; q < 4; ++q) { sv[j][q] = NEG_INF_; sx[j][q] = INT_MAX; }
    }

    const char* plane = (w == 0) ? (const char*)f2hi
                      : (w == 1) ? (const char*)f2lo
                      : (w == 2) ? (const char*)f1hi
                      :            (const char*)f1lo;
    const bf16x8* ldsAh = (const bf16x8*)(smem);
    const bf16x8* ldsAl = (const bf16x8*)(smem + 8192);
    const bf16x8* ldsBh = (const bf16x8*)(smem + 16384);
    const bf16x8* ldsBl = (const bf16x8*)(smem + 24576);

    for (int mc = 0; mc < MPS_; ++mc) {
        const int m0 = (s * MPS_ + mc) * BM_;

        // per-thread staging source pointers (8 rounds; rows clamped)
        const char* gsrc[8];
        {
            const int rowbase = ((w < 2) ? m0 : n0) + (l & 15);
            const int koff = (l >> 4) * 16;   // bytes (8 bf16)
            #pragma unroll
            for (int r = 0; r < 8; ++r) {
                int row = rowbase + r * 16; if (row > N_ - 1) row = N_ - 1;
                gsrc[r] = plane + (size_t)row * (C_ * 2) + koff;
            }
        }

        f32x4 acc[8][2];
        #pragma unroll
        for (int mt = 0; mt < 8; ++mt) { acc[mt][0] = 0.0f; acc[mt][1] = 0.0f; }

        for (int kc = 0; kc < C_ / BK_; ++kc) {
            __syncthreads();    // previous chunk's frags consumed
            #pragma unroll
            for (int r = 0; r < 8; ++r)
                gload16(gsrc[r] + kc * (BK_ * 2), smem + (w * 8 + r) * 1024);
            __syncthreads();    // staging complete (compiler drains vmcnt)

            bf16x8 bh0 = ldsBh[(2*w + 0) * 64 + l];
            bf16x8 bl0 = ldsBl[(2*w + 0) * 64 + l];
            bf16x8 bh1 = ldsBh[(2*w + 1) * 64 + l];
            bf16x8 bl1 = ldsBl[(2*w + 1) * 64 + l];
            #pragma unroll
            for (int mt = 0; mt < 8; ++mt) {
                bf16x8 ah = ldsAh[mt * 64 + l];
                bf16x8 al = ldsAl[mt * 64 + l];
                acc[mt][0] = __builtin_amdgcn_mfma_f32_16x16x32_bf16(ah, bh0, acc[mt][0], 0, 0, 0);
                acc[mt][0] = __builtin_amdgcn_mfma_f32_16x16x32_bf16(ah, bl0, acc[mt][0], 0, 0, 0);
                acc[mt][0] = __builtin_amdgcn_mfma_f32_16x16x32_bf16(al, bh0, acc[mt][0], 0, 0, 0);
                acc[mt][1] = __builtin_amdgcn_mfma_f32_16x16x32_bf16(ah, bh1, acc[mt][1], 0, 0, 0);
                acc[mt][1] = __builtin_amdgcn_mfma_f32_16x16x32_bf16(ah, bl1, acc[mt][1], 0, 0, 0);
                acc[mt][1] = __builtin_amdgcn_mfma_f32_16x16x32_bf16(al, bh1, acc[mt][1], 0, 0, 0);
            }
        }

        // fold chunk scores into per-lane top-4 (m ascending within lane)
        const int mrow = m0 + ((l >> 4) << 2);
        #pragma unroll
        for (int j = 0; j < 2; ++j) {
            #pragma unroll
            for (int mt = 0; mt < 8; ++mt) {
                #pragma unroll
                for (int q = 0; q < 4; ++q) {
                    const int m = mrow + mt * 16 + q;
                    float v = acc[mt][j][q];
                    if (m >= N_) v = NEG_INF_;
                    ins4(v, m, sv[j], sx[j]);
                }
            }
        }
    }

    // ---- block epilogue: merge 4 lane-partitions -> per-n top-4 ----
    __syncthreads();
    {
        float* mv = (float*)smem;            // [128][16]
        int*   mi = (int*)(smem + 8192);     // [128][16]
        const int g = l >> 4;
        #pragma unroll
        for (int j = 0; j < 2; ++j) {
            const int nl = (2*w + j) * 16 + (l & 15);
            #pragma unroll
            for (int q = 0; q < 4; ++q) {
                mv[nl * 16 + g * 4 + q] = sv[j][q];
                mi[nl * 16 + g * 4 + q] = sx[j][q];
            }
        }
        __syncthreads();
        if (tid < BN_) {
            const int n = n0 + tid;
            if (n < N_) {
                float bv[4]; int bi[4];
                #pragma unroll
                for (int q = 0; q < 4; ++q) { bv[q] = NEG_INF_; bi[q] = INT_MAX; }
                for (int q = 0; q < 16; ++q)
                    ins4tb(mv[tid * 16 + q], mi[tid * 16 + q], bv, bi);
                const size_t base = ((size_t)s * N_ + n) * 4;
                #pragma unroll
                for (int q = 0; q < 4; ++q) { pval[base + q] = bv[q]; pidx[base + q] = bi[q]; }
            }
        }
    }
}

// ---------------------------------------------------------------------------
// Kernel B: merge split candidates -> approx top-8 -> exact fp32 rescore
// -> exact top-4 (val desc, idx asc). One wave per pixel n.
// ---------------------------------------------------------------------------
__global__ __launch_bounds__(256)
void rescore_kernel(const float* __restrict__ pval, const int* __restrict__ pidx,
                    const float* __restrict__ f1T, const float* __restrict__ f2T,
                    float* __restrict__ rval, int* __restrict__ ridx)
{
    __shared__ float candv[4][8];
    __shared__ int   candi[4][8];
    const int w = threadIdx.x >> 6;
    const int l = threadIdx.x & 63;
    const int n = blockIdx.x * 4 + w;
    if (n >= N_) return;   // N_ = 11408 = 4*2852: never taken, kept for safety

    // load 60 candidates (15 splits x 4); idx are globally distinct
    float cv = NEG_INF_; int ci = INT_MAX;
    if (l < SPL_ * 4) {
        const int sp = l >> 2, q = l & 3;
        const size_t base = ((size_t)sp * N_ + n) * 4;
        cv = pval[base + q]; ci = pidx[base + q];
    }

    // extract approx top-8 (val desc, idx asc)
    #pragma unroll
    for (int t = 0; t < 8; ++t) {
        float mv = cv; int mi_ = ci;
        #pragma unroll
        for (int off = 1; off < 64; off <<= 1) {
            float ov = __shfl_xor(mv, off);
            int   oi = __shfl_xor(mi_, off);
            if (ov > mv || (ov == mv && oi < mi_)) { mv = ov; mi_ = oi; }
        }
        if (l == 0) { candv[w][t] = mv; candi[w][t] = mi_; }
        if (cv == mv && ci == mi_) cv = NEG_INF_;   // remove winner (unique idx)
    }
    __syncthreads();

    // exact fp32 rescore: 8 groups of 8 lanes, group g -> candidate g
    const int g = l >> 3, j = l & 7;
    const int m = candi[w][g];
    float acc = 0.0f;
    {
        const float4* pa = (const float4*)(f1T + (size_t)n * C_) + j * 8;
        const float4* pb = (const float4*)(f2T + (size_t)m * C_) + j * 8;
        #pragma unroll
        for (int i = 0; i < 8; ++i) {
            float4 a = pa[i], b = pb[i];
            acc = fmaf(a.x, b.x, acc); acc = fmaf(a.y, b.y, acc);
            acc = fmaf(a.z, b.z, acc); acc = fmaf(a.w, b.w, acc);
        }
        acc += __shfl_xor(acc, 1);
        acc += __shfl_xor(acc, 2);
        acc += __shfl_xor(acc, 4);
    }

    // gather 8 exact scores, exact top-4
    float bv[4]; int bi[4];
    #pragma unroll
    for (int q = 0; q < 4; ++q) { bv[q] = NEG_INF_; bi[q] = INT_MAX; }
    #pragma unroll
    for (int g2 = 0; g2 < 8; ++g2) {
        float vg = __shfl(acc, g2 * 8);
        ins4tb(vg, candi[w][g2], bv, bi);
    }
    if (l == 0) {
        float4 fv; fv.x = bv[0]; fv.y = bv[1]; fv.z = bv[2]; fv.w = bv[3];
        int4   iv; iv.x = bi[0]; iv.y = bi[1]; iv.z = bi[2]; iv.w = bi[3];
        *(float4*)(rval + (size_t)n * 4) = fv;
        *(int4*)(ridx + (size_t)n * 4)   = iv;
    }
}

// ---------------------------------------------------------------------------
// Kernel C: 5-level bilinear scatter (per-pixel private 405 channels).
// ---------------------------------------------------------------------------
__global__ __launch_bounds__(256)
void scatter2_kernel(const float* __restrict__ rval, const int* __restrict__ ridx,
                     const float* __restrict__ dflow, float* __restrict__ out)
{
    const int n = blockIdx.x * blockDim.x + threadIdx.x;
    if (n >= N_) return;

    float4 fv = *(const float4*)(rval + (size_t)n * 4);
    int4   iv = *(const int4*)(ridx + (size_t)n * 4);
    const float v[4]  = {fv.x, fv.y, fv.z, fv.w};
    const int   id[4] = {iv.x, iv.y, iv.z, iv.w};

    const int   y0  = n / W_;
    const int   x0  = n - y0 * W_;
    const float df0 = dflow[n];
    const float df1 = dflow[N_ + n];
    float ccy[4], ccx[4], cr[4];
    #pragma unroll
    for (int k = 0; k < 4; ++k) {
        const int m  = id[k];
        const int y1 = m / W_;
        const int x1 = m - y1 * W_;
        cr[k]  = v[k] * 0.0625f;
        ccy[k] = (float)(y1 - y0) - df1;
        ccx[k] = (float)(x1 - x0) - df0;
    }

    float scale = 1.0f;
    for (int lvl = 0; lvl < LEVELS_; ++lvl) {
        float bins[WIN_ * WIN_];
        for (int jj = 0; jj < WIN_ * WIN_; ++jj) bins[jj] = 0.0f;
        #pragma unroll
        for (int k = 0; k < 4; ++k) {
            const float cy = ccy[k] * scale;
            const float cx = ccx[k] * scale;
            const float yf = floorf(cy), xf = floorf(cx);
            const float dy = cy - yf,    dx = cx - xf;
            const float cyv[4] = {yf, yf, yf + 1.0f, yf + 1.0f};
            const float cxv[4] = {xf, xf + 1.0f, xf, xf + 1.0f};
            const float wv[4]  = {(1.0f-dy)*(1.0f-dx), (1.0f-dy)*dx, dy*(1.0f-dx), dy*dx};
            #pragma unroll
            for (int c = 0; c < 4; ++c) {
                if (fabsf(cyv[c]) <= (float)SR_ && fabsf(cxv[c]) <= (float)SR_) {
                    const int iy = (int)cyv[c] + SR_;
                    const int ix = (int)cxv[c] + SR_;
                    bins[iy * WIN_ + ix] += wv[c] * cr[k];
                }
            }
        }
        const size_t obase = (size_t)lvl * (WIN_ * WIN_) * N_ + n;
        for (int jj = 0; jj < WIN_ * WIN_; ++jj)
            out[obase + (size_t)jj * N_] = bins[jj];
        scale *= 0.5f;
    }
}

// ===========================================================================
// Fallback path (round-2 proven fp32 kernels) if workspace is too small.
// ===========================================================================
#define TILE_   64
#define KC_     16
#define NT_     ((N_ + TILE_ - 1) / TILE_)

__global__ __launch_bounds__(256)
void knn_partial_kernel(const float* __restrict__ f1, const float* __restrict__ f2,
                        float* __restrict__ pval, int* __restrict__ pidx,
                        int mt_per_split)
{
    __shared__ float As[KC_][TILE_];
    __shared__ float Bs[KC_][TILE_];
    __shared__ float Ss[TILE_][TILE_ + 1];
    const int nb = blockIdx.x, split = blockIdx.y, n0 = nb * TILE_;
    const int tid = threadIdx.x, tx = tid & 15, ty = tid >> 4;
    const int lr = tid >> 4, lc = (tid & 15) * 4;
    const bool edge_n = (n0 + TILE_ > N_);
    float rv0 = NEG_INF_, rv1 = NEG_INF_, rv2 = NEG_INF_, rv3 = NEG_INF_;
    int ri0 = 0, ri1 = 0, ri2 = 0, ri3 = 0;
    const int mt_begin = split * mt_per_split;
    const int mt_end = (mt_begin + mt_per_split < NT_) ? (mt_begin + mt_per_split) : NT_;
    for (int mt = mt_begin; mt < mt_end; ++mt) {
        const int m0 = mt * TILE_;
        const bool edge_m = (m0 + TILE_ > N_);
        float acc[4][4];
        #pragma unroll
        for (int i = 0; i < 4; ++i) {
            #pragma unroll
            for (int j = 0; j < 4; ++j) acc[i][j] = 0.0f;
        }
        for (int kc = 0; kc < C_; kc += KC_) {
            __syncthreads();
            const float* a_src = f1 + (size_t)(kc + lr) * N_;
            const float* b_src = f2 + (size_t)(kc + lr) * N_;
            if (!edge_n) {
                *(float4*)&As[lr][lc] = *(const float4*)(a_src + n0 + lc);
            } else {
                for (int i = 0; i < 4; ++i) {
                    int n = n0 + lc + i; if (n > N_ - 1) n = N_ - 1;
                    As[lr][lc + i] = a_src[n];
                }
            }
            if (!edge_m) {
                *(float4*)&Bs[lr][lc] = *(const float4*)(b_src + m0 + lc);
            } else {
                for (int i = 0; i < 4; ++i) {
                    int m = m0 + lc + i; if (m > N_ - 1) m = N_ - 1;
                    Bs[lr][lc + i] = b_src[m];
                }
            }
            __syncthreads();
            #pragma unroll
            for (int k = 0; k < KC_; ++k) {
                const float4 a = *(const float4*)&As[k][ty * 4];
                const float4 b = *(const float4*)&Bs[k][tx * 4];
                acc[0][0]=fmaf(a.x,b.x,acc[0][0]); acc[0][1]=fmaf(a.x,b.y,acc[0][1]);
                acc[0][2]=fmaf(a.x,b.z,acc[0][2]); acc[0][3]=fmaf(a.x,b.w,acc[0][3]);
                acc[1][0]=fmaf(a.y,b.x,acc[1][0]); acc[1][1]=fmaf(a.y,b.y,acc[1][1]);
                acc[1][2]=fmaf(a.y,b.z,acc[1][2]); acc[1][3]=fmaf(a.y,b.w,acc[1][3]);
                acc[2][0]=fmaf(a.z,b.x,acc[2][0]); acc[2][1]=fmaf(a.z,b.y,acc[2][1]);
                acc[2][2]=fmaf(a.z,b.z,acc[2][2]); acc[2][3]=fmaf(a.z,b.w,acc[2][3]);
                acc[3][0]=fmaf(a.w,b.x,acc[3][0]); acc[3][1]=fmaf(a.w,b.y,acc[3][1]);
                acc[3][2]=fmaf(a.w,b.z,acc[3][2]); acc[3][3]=fmaf(a.w,b.w,acc[3][3]);
            }
        }
        __syncthreads();
        #pragma unroll
        for (int i = 0; i < 4; ++i) {
            #pragma unroll
            for (int j = 0; j < 4; ++j) Ss[ty*4+i][tx*4+j] = acc[i][j];
        }
        __syncthreads();
        if (tid < TILE_) {
            const int mlim = edge_m ? (N_ - m0) : TILE_;
            for (int m = 0; m < mlim; ++m) {
                const float sc = Ss[tid][m];
                if (sc > rv3) {
                    const int mi = m0 + m;
                    if (sc > rv1) {
                        if (sc > rv0) { rv3=rv2; ri3=ri2; rv2=rv1; ri2=ri1; rv1=rv0; ri1=ri0; rv0=sc; ri0=mi; }
                        else          { rv3=rv2; ri3=ri2; rv2=rv1; ri2=ri1; rv1=sc; ri1=mi; }
                    } else {
                        if (sc > rv2) { rv3=rv2; ri3=ri2; rv2=sc; ri2=mi; }
                        else          { rv3=sc; ri3=mi; }
                    }
                }
            }
        }
        __syncthreads();
    }
    if (tid < TILE_) {
        const int n = n0 + tid;
        if (n < N_) {
            const size_t base = ((size_t)split * N_ + n) * 4;
            pval[base+0]=rv0; pidx[base+0]=ri0; pval[base+1]=rv1; pidx[base+1]=ri1;
            pval[base+2]=rv2; pidx[base+2]=ri2; pval[base+3]=rv3; pidx[base+3]=ri3;
        }
    }
}

__global__ __launch_bounds__(256)
void scatter_kernel(const float* __restrict__ pval, const int* __restrict__ pidx,
                    const float* __restrict__ dflow, float* __restrict__ out, int splits)
{
    const int n = blockIdx.x * blockDim.x + threadIdx.x;
    if (n >= N_) return;
    float v[4] = {NEG_INF_, NEG_INF_, NEG_INF_, NEG_INF_};
    int id[4] = {0, 0, 0, 0};
    for (int sp = 0; sp < splits; ++sp) {
        const size_t base = ((size_t)sp * N_ + n) * 4;
        #pragma unroll
        for (int k = 0; k < 4; ++k) ins4tb(pval[base + k], pidx[base + k], v, id);
    }
    const int y0 = n / W_, x0 = n - y0 * W_;
    const float df0 = dflow[n], df1 = dflow[N_ + n];
    float ccy[4], ccx[4], cr[4];
    #pragma unroll
    for (int k = 0; k < 4; ++k) {
        const int m = id[k], y1 = m / W_, x1 = m - y1 * W_;
        cr[k] = v[k] * 0.0625f;
        ccy[k] = (float)(y1 - y0) - df1; ccx[k] = (float)(x1 - x0) - df0;
    }
    float scale = 1.0f;
    for (int lvl = 0; lvl < LEVELS_; ++lvl) {
        float bins[WIN_ * WIN_];
        for (int jj = 0; jj < WIN_ * WIN_; ++jj) bins[jj] = 0.0f;
        #pragma unroll
        for (int k = 0; k < 4; ++k) {
            const float cy = ccy[k] * scale, cx = ccx[k] * scale;
            const float yf = floorf(cy), xf = floorf(cx);
            const float dy = cy - yf, dx = cx - xf;
            const float cyv[4] = {yf, yf, yf + 1.0f, yf + 1.0f};
            const float cxv[4] = {xf, xf + 1.0f, xf, xf + 1.0f};
            const float wv[4] = {(1.0f-dy)*(1.0f-dx), (1.0f-dy)*dx, dy*(1.0f-dx), dy*dx};
            #pragma unroll
            for (int c = 0; c < 4; ++c) {
                if (fabsf(cyv[c]) <= (float)SR_ && fabsf(cxv[c]) <= (float)SR_) {
                    bins[((int)cyv[c] + SR_) * WIN_ + (int)cxv[c] + SR_] += wv[c] * cr[k];
                }
            }
        }
        const size_t obase = (size_t)lvl * (WIN_ * WIN_) * N_ + n;
        for (int jj = 0; jj < WIN_ * WIN_; ++jj) out[obase + (size_t)jj * N_] = bins[jj];
        scale *= 0.5f;
    }
}

// ---------------------------------------------------------------------------
extern "C" void kernel_launch(void* const* d_in, const int* in_sizes, int n_in,
                              void* d_out, int out_size, void* d_ws, size_t ws_size,
                              hipStream_t stream)
{
    const float* f1    = (const float*)d_in[0];
    const float* f2    = (const float*)d_in[1];
    const float* dflow = (const float*)d_in[2];
    float*       out   = (float*)d_out;

    // ---- MFMA path workspace layout ----
    const size_t NC2   = (size_t)N_ * C_ * 2;           // bf16 plane bytes
    const size_t o_f2hi = 0;
    const size_t o_f2lo = NC2;
    const size_t o_f1hi = 2 * NC2;
    const size_t o_f1lo = 3 * NC2;
    const size_t o_f1T  = 4 * NC2;                      // fp32 = 2*NC2 bytes
    const size_t o_f2T  = 6 * NC2;
    const size_t o_pval = 8 * NC2;
    const size_t sz_p   = (size_t)SPL_ * N_ * 4 * 4;
    const size_t o_pidx = o_pval + sz_p;
    const size_t o_rval = o_pidx + sz_p;
    const size_t sz_r   = (size_t)N_ * 4 * 4;
    const size_t o_ridx = o_rval + sz_r;
    const size_t total  = o_ridx + sz_r;

    if (ws_size >= total) {
        char* ws = (char*)d_ws;
        unsigned short* f2hi = (unsigned short*)(ws + o_f2hi);
        unsigned short* f2lo = (unsigned short*)(ws + o_f2lo);
        unsigned short* f1hi = (unsigned short*)(ws + o_f1hi);
        unsigned short* f1lo = (unsigned short*)(ws + o_f1lo);
        float* f1T  = (float*)(ws + o_f1T);
        float* f2T  = (float*)(ws + o_f2T);
        float* pval = (float*)(ws + o_pval);
        int*   pidx = (int*)(ws + o_pidx);
        float* rval = (float*)(ws + o_rval);
        int*   ridx = (int*)(ws + o_ridx);

        dim3 gp(C_ / 64, (N_ + 63) / 64, 2);
        prep_kernel<<<gp, 256, 0, stream>>>(f1, f2, f1hi, f1lo, f2hi, f2lo, f1T, f2T);

        dim3 ga(NTB_, SPL_);
        knn_mfma_kernel<<<ga, 256, 0, stream>>>(f1hi, f1lo, f2hi, f2lo, pval, pidx);

        rescore_kernel<<<(N_ + 3) / 4, 256, 0, stream>>>(pval, pidx, f1T, f2T, rval, ridx);

        scatter2_kernel<<<(N_ + 255) / 256, 256, 0, stream>>>(rval, ridx, dflow, out);
    } else {
        // fallback: round-2 fp32 path
        const size_t per_split = (size_t)N_ * 32u;
        int splits = 1;
        while (splits < 8 && (size_t)(splits * 2) * per_split <= ws_size) splits *= 2;
        float* pval = (float*)d_ws;
        int*   pidx = (int*)((char*)d_ws + (size_t)splits * N_ * 4 * sizeof(float));
        const int mps = (NT_ + splits - 1) / splits;
        dim3 gridA(NT_, splits);
        knn_partial_kernel<<<gridA, 256, 0, stream>>>(f1, f2, pval, pidx, mps);
        scatter_kernel<<<(N_ + 255) / 256, 256, 0, stream>>>(pval, pidx, dflow, out, splits);
    }
}

// Round 5
// 485.794 us; speedup vs baseline: 2.6342x; 1.0274x over previous
//
#include <hip/hip_runtime.h>
#include <cstddef>
#include <climits>

// Problem constants (fixed by reference setup_inputs)
#define H_      92
#define W_      124
#define N_      (H_ * W_)      // 11408
#define C_      256
#define SR_     4
#define WIN_    9
#define LEVELS_ 5
#define NEG_INF_ (-1.0e30f)

// ---- MFMA path geometry ----
#define BM_     128            // m per block-chunk
#define BN_     128            // n-stripe per block
#define BK_     32             // k-chunk
#define MT_     ((N_ + BM_ - 1) / BM_)   // 90 m-chunks
#define NTB_    ((N_ + BN_ - 1) / BN_)   // 90 n-blocks
#define SPL_    15             // m-splits (90 = 15*6)
#define MPS_    (MT_ / SPL_)   // 6 m-chunks per split
#define STEPS_  (MPS_ * 8)     // 48 k-steps per block

typedef __attribute__((ext_vector_type(8))) short bf16x8;
typedef __attribute__((ext_vector_type(4))) float f32x4;

#define AS1 __attribute__((address_space(1)))
#define AS3 __attribute__((address_space(3)))

__device__ __forceinline__ void gload16(const void* gp, void* lp) {
    __builtin_amdgcn_global_load_lds((const AS1 void*)gp, (AS3 void*)lp, 16, 0, 0);
}

__device__ __forceinline__ unsigned short f2bf(float x) {
    unsigned u = __float_as_uint(x);
    u = (u + 0x7fffu + ((u >> 16) & 1u)) >> 16;
    return (unsigned short)u;
}
__device__ __forceinline__ float bf2f(unsigned short h) {
    return __uint_as_float(((unsigned)h) << 16);
}

// sorted-desc top-4 insert, strict > (ascending-index scan => lowest idx on ties)
// slot conditions: p0: c1; p1: !c1&&c2; p2: !c2&&c3; p3: !c3.
__device__ __forceinline__ void ins4(float v, int m, float s[4], int ix[4]) {
    if (v > s[3]) {
        const bool c1 = v > s[0];
        const bool c2 = v > s[1];
        const bool c3 = v > s[2];
        const float n0 = c1 ? v : s[0];               const int m0_ = c1 ? m : ix[0];
        const float n1 = c1 ? s[0] : (c2 ? v : s[1]); const int m1 = c1 ? ix[0] : (c2 ? m : ix[1]);
        const float n2 = c2 ? s[1] : (c3 ? v : s[2]); const int m2 = c2 ? ix[1] : (c3 ? m : ix[2]);
        const float n3 = c3 ? s[2] : v;               const int m3 = c3 ? ix[2] : m;
        s[0] = n0; s[1] = n1; s[2] = n2; s[3] = n3;
        ix[0] = m0_; ix[1] = m1; ix[2] = m2; ix[3] = m3;
    }
}

// tie-breaking top-4 insert: order by (val desc, idx asc)
__device__ __forceinline__ void ins4tb(float v, int m, float s[4], int ix[4]) {
    const bool g3 = (v > s[3]) || (v == s[3] && m < ix[3]);
    if (g3) {
        const bool c1 = (v > s[0]) || (v == s[0] && m < ix[0]);
        const bool c2 = (v > s[1]) || (v == s[1] && m < ix[1]);
        const bool c3 = (v > s[2]) || (v == s[2] && m < ix[2]);
        const float n0 = c1 ? v : s[0];               const int m0_ = c1 ? m : ix[0];
        const float n1 = c1 ? s[0] : (c2 ? v : s[1]); const int m1 = c1 ? ix[0] : (c2 ? m : ix[1]);
        const float n2 = c2 ? s[1] : (c3 ? v : s[2]); const int m2 = c2 ? ix[1] : (c3 ? m : ix[2]);
        const float n3 = c3 ? s[2] : v;               const int m3 = c3 ? ix[2] : m;
        s[0] = n0; s[1] = n1; s[2] = n2; s[3] = n3;
        ix[0] = m0_; ix[1] = m1; ix[2] = m2; ix[3] = m3;
    }
}

// ---------------------------------------------------------------------------
// Kernel P: transpose + split-bf16 conversion.
//  z=0: f1 -> f1T fp32 [N][C], f1hi/f1lo bf16 [N][C]
//  z=1: f2 -> f2T fp32 [N][C], f2hi/f2lo bf16 [N][C]
// ---------------------------------------------------------------------------
__global__ __launch_bounds__(256)
void prep_kernel(const float* __restrict__ f1, const float* __restrict__ f2,
                 unsigned short* __restrict__ f1hi, unsigned short* __restrict__ f1lo,
                 unsigned short* __restrict__ f2hi, unsigned short* __restrict__ f2lo,
                 float* __restrict__ f1T, float* __restrict__ f2T)
{
    __shared__ float tile[64][65];
    const int c0 = blockIdx.x * 64;
    const int n0 = blockIdx.y * 64;
    const int z  = blockIdx.z;
    const float* src = z ? f2 : f1;
    unsigned short* thi = z ? f2hi : f1hi;
    unsigned short* tlo = z ? f2lo : f1lo;
    float* tT = z ? f2T : f1T;

    const int t  = threadIdx.x;
    const int r  = t >> 4;          // 0..15
    const int c4 = (t & 15) * 4;

    if (n0 + 64 <= N_) {
        #pragma unroll
        for (int i = 0; i < 4; ++i) {
            const int c = c0 + r + i * 16;
            const float4 v = *(const float4*)(src + (size_t)c * N_ + n0 + c4);
            tile[r + i*16][c4+0] = v.x; tile[r + i*16][c4+1] = v.y;
            tile[r + i*16][c4+2] = v.z; tile[r + i*16][c4+3] = v.w;
        }
    } else {
        #pragma unroll
        for (int i = 0; i < 4; ++i) {
            const int c = c0 + r + i * 16;
            for (int j = 0; j < 4; ++j) {
                int n = n0 + c4 + j; if (n > N_ - 1) n = N_ - 1;
                tile[r + i*16][c4 + j] = src[(size_t)c * N_ + n];
            }
        }
    }
    __syncthreads();

    #pragma unroll
    for (int i = 0; i < 4; ++i) {
        const int nl = r + i * 16;
        const int n  = n0 + nl;
        if (n < N_) {
            float x0 = tile[c4+0][nl], x1 = tile[c4+1][nl];
            float x2 = tile[c4+2][nl], x3 = tile[c4+3][nl];
            float4 fv; fv.x = x0; fv.y = x1; fv.z = x2; fv.w = x3;
            *(float4*)(tT + (size_t)n * C_ + c0 + c4) = fv;
            unsigned short h0 = f2bf(x0), h1 = f2bf(x1), h2 = f2bf(x2), h3 = f2bf(x3);
            ushort4 hv; hv.x = h0; hv.y = h1; hv.z = h2; hv.w = h3;
            *(ushort4*)(thi + (size_t)n * C_ + c0 + c4) = hv;
            ushort4 lv;
            lv.x = f2bf(x0 - bf2f(h0)); lv.y = f2bf(x1 - bf2f(h1));
            lv.z = f2bf(x2 - bf2f(h2)); lv.w = f2bf(x3 - bf2f(h3));
            *(ushort4*)(tlo + (size_t)n * C_ + c0 + c4) = lv;
        }
    }
}

// ---------------------------------------------------------------------------
// Kernel A (MFMA): split-bf16 scores + per-lane-partition top-4 candidates.
// 256 thr = 4 waves in a 2x2 grid; wave (wm,wn) owns a 64m x 64n tile of the
// 128x128 block tile. Double-buffered LDS (2 x 32KB), one barrier per k-step:
// stage chunk t+1 into buf^1 while computing chunk t from buf.
// Per step per wave: 8 A-frag + 8 B-frag ds_read_b128, 48 MFMAs.
// D row = m = wm*64 + mt*16 + (l>>4)*4 + reg ; col = n = wn*64 + nt*16 + (l&15).
// Staging: wave w stages one plane (w0:f1hi/B, w1:f1lo, w2:f2hi/A, w3:f2lo).
// ---------------------------------------------------------------------------
__global__ __launch_bounds__(256, 2)
void knn_mfma_kernel(const unsigned short* __restrict__ f1hi, const unsigned short* __restrict__ f1lo,
                     const unsigned short* __restrict__ f2hi, const unsigned short* __restrict__ f2lo,
                     float* __restrict__ pval, int* __restrict__ pidx)
{
    __shared__ __align__(16) char smem[65536];   // 2 buffers x 32KB; epilogue reuses

    const int tid = threadIdx.x;
    const int w   = tid >> 6;
    const int l   = tid & 63;
    const int wm  = w >> 1;          // wave m-row (0..1)
    const int wn  = w & 1;           // wave n-col (0..1)
    const int n0  = blockIdx.x * BN_;
    const int s   = blockIdx.y;

    const char* myplane = (w == 0) ? (const char*)f1hi    // B hi (n rows)
                        : (w == 1) ? (const char*)f1lo    // B lo
                        : (w == 2) ? (const char*)f2hi    // A hi (m rows)
                        :            (const char*)f2lo;   // A lo

    // per-lane top-4 state for the lane's four n columns (nt = 0..3)
    float sv[4][4]; int sx[4][4];
    #pragma unroll
    for (int nt = 0; nt < 4; ++nt) {
        #pragma unroll
        for (int q = 0; q < 4; ++q) { sv[nt][q] = NEG_INF_; sx[nt][q] = INT_MAX; }
    }

    f32x4 acc[4][4];
    #pragma unroll
    for (int mt = 0; mt < 4; ++mt) {
        #pragma unroll
        for (int nt = 0; nt < 4; ++nt) acc[mt][nt] = 0.0f;
    }

    // ---- staging helper: stage step t's 32x(128rows) chunk of my plane ----
    // LDS layout inside a buffer: Bh@0 Bl@8K Ah@16K Al@24K; each plane 8KB =
    // 8 rounds of 1KB; round r holds rows (l&15)+16r, kbytes (l>>4)*16.
    const int lrow  = l & 15;
    const int kbl   = (l >> 4) * 16;      // lane byte offset within 64B k-slice

    #define STAGE_(t_, buf_)                                                     \
    {                                                                            \
        const int mc_ = (t_) >> 3, kc_ = (t_) & 7;                               \
        const int rowbase_ = ((w < 2) ? n0 : (s * MPS_ + mc_) * BM_) + lrow;     \
        const int kbyte_ = kc_ * 64 + kbl;                                       \
        _Pragma("unroll")                                                        \
        for (int r = 0; r < 8; ++r) {                                            \
            int row_ = rowbase_ + r * 16; if (row_ > N_ - 1) row_ = N_ - 1;      \
            gload16(myplane + (size_t)row_ * (C_ * 2) + kbyte_,                  \
                    (buf_) + (w * 8 + r) * 1024);                                \
        }                                                                        \
    }

    // prologue
    STAGE_(0, smem);
    __syncthreads();

    int cur = 0;
    for (int t = 0; t < STEPS_; ++t) {
        if (t + 1 < STEPS_) STAGE_(t + 1, smem + ((cur ^ 1) << 15));

        const char* buf = smem + (cur << 15);
        const bf16x8* Bh = (const bf16x8*)(buf);
        const bf16x8* Bl = (const bf16x8*)(buf + 8192);
        const bf16x8* Ah = (const bf16x8*)(buf + 16384);
        const bf16x8* Al = (const bf16x8*)(buf + 24576);

        bf16x8 bh[4], bl[4];
        #pragma unroll
        for (int nt = 0; nt < 4; ++nt) {
            bh[nt] = Bh[(wn * 4 + nt) * 64 + l];
            bl[nt] = Bl[(wn * 4 + nt) * 64 + l];
        }
        #pragma unroll
        for (int mt = 0; mt < 4; ++mt) {
            const bf16x8 ah = Ah[(wm * 4 + mt) * 64 + l];
            const bf16x8 al = Al[(wm * 4 + mt) * 64 + l];
            #pragma unroll
            for (int nt = 0; nt < 4; ++nt) {
                acc[mt][nt] = __builtin_amdgcn_mfma_f32_16x16x32_bf16(ah, bh[nt], acc[mt][nt], 0, 0, 0);
                acc[mt][nt] = __builtin_amdgcn_mfma_f32_16x16x32_bf16(ah, bl[nt], acc[mt][nt], 0, 0, 0);
                acc[mt][nt] = __builtin_amdgcn_mfma_f32_16x16x32_bf16(al, bh[nt], acc[mt][nt], 0, 0, 0);
            }
        }

        if ((t & 7) == 7) {   // end of an m-chunk: fold acc into running top-4
            const int mc = t >> 3;
            const int mbase = (s * MPS_ + mc) * BM_ + wm * 64 + ((l >> 4) << 2);
            #pragma unroll
            for (int nt = 0; nt < 4; ++nt) {
                #pragma unroll
                for (int mt = 0; mt < 4; ++mt) {
                    #pragma unroll
                    for (int q = 0; q < 4; ++q) {
                        const int m = mbase + mt * 16 + q;
                        float v = acc[mt][nt][q];
                        if (m >= N_) v = NEG_INF_;
                        ins4(v, m, sv[nt], sx[nt]);
                        acc[mt][nt][q] = 0.0f;
                    }
                }
            }
        }
        __syncthreads();
        cur ^= 1;
    }
    #undef STAGE_

    // ---- block epilogue: merge 8 lane-partitions per n -> per-n top-4 ----
    // mv/mi: [128 n][8 g][4 q], padded row stride 33 words (bank-conflict-free)
    {
        float* mv = (float*)smem;             // 128*33 floats = 16.5KB
        int*   mi = (int*)(smem + 20480);     // 16.5KB at +20KB
        const int g = wm * 4 + (l >> 4);
        #pragma unroll
        for (int nt = 0; nt < 4; ++nt) {
            const int nl = wn * 64 + nt * 16 + (l & 15);
            #pragma unroll
            for (int q = 0; q < 4; ++q) {
                mv[nl * 33 + g * 4 + q] = sv[nt][q];
                mi[nl * 33 + g * 4 + q] = sx[nt][q];
            }
        }
        __syncthreads();
        if (tid < BN_) {
            const int n = n0 + tid;
            if (n < N_) {
                float bv[4]; int bi[4];
                #pragma unroll
                for (int q = 0; q < 4; ++q) { bv[q] = NEG_INF_; bi[q] = INT_MAX; }
                for (int e = 0; e < 32; ++e)
                    ins4tb(mv[tid * 33 + e], mi[tid * 33 + e], bv, bi);
                const size_t base = ((size_t)s * N_ + n) * 4;
                #pragma unroll
                for (int q = 0; q < 4; ++q) { pval[base + q] = bv[q]; pidx[base + q] = bi[q]; }
            }
        }
    }
}

// ---------------------------------------------------------------------------
// Kernel B: merge split candidates -> approx top-8 -> exact fp32 rescore
// -> exact top-4 (val desc, idx asc). One wave per pixel n.
// ---------------------------------------------------------------------------
__global__ __launch_bounds__(256)
void rescore_kernel(const float* __restrict__ pval, const int* __restrict__ pidx,
                    const float* __restrict__ f1T, const float* __restrict__ f2T,
                    float* __restrict__ rval, int* __restrict__ ridx)
{
    __shared__ float candv[4][8];
    __shared__ int   candi[4][8];
    const int w = threadIdx.x >> 6;
    const int l = threadIdx.x & 63;
    const int n = blockIdx.x * 4 + w;
    if (n >= N_) return;   // N_ = 11408 = 4*2852: never taken, kept for safety

    // load 60 candidates (15 splits x 4); idx are globally distinct
    float cv = NEG_INF_; int ci = INT_MAX;
    if (l < SPL_ * 4) {
        const int sp = l >> 2, q = l & 3;
        const size_t base = ((size_t)sp * N_ + n) * 4;
        cv = pval[base + q]; ci = pidx[base + q];
    }

    // extract approx top-8 (val desc, idx asc)
    #pragma unroll
    for (int t = 0; t < 8; ++t) {
        float mv = cv; int mi_ = ci;
        #pragma unroll
        for (int off = 1; off < 64; off <<= 1) {
            float ov = __shfl_xor(mv, off);
            int   oi = __shfl_xor(mi_, off);
            if (ov > mv || (ov == mv && oi < mi_)) { mv = ov; mi_ = oi; }
        }
        if (l == 0) { candv[w][t] = mv; candi[w][t] = mi_; }
        if (cv == mv && ci == mi_) cv = NEG_INF_;   // remove winner (unique idx)
    }
    __syncthreads();

    // exact fp32 rescore: 8 groups of 8 lanes, group g -> candidate g
    const int g = l >> 3, j = l & 7;
    const int m = candi[w][g];
    float acc = 0.0f;
    {
        const float4* pa = (const float4*)(f1T + (size_t)n * C_) + j * 8;
        const float4* pb = (const float4*)(f2T + (size_t)m * C_) + j * 8;
        #pragma unroll
        for (int i = 0; i < 8; ++i) {
            float4 a = pa[i], b = pb[i];
            acc = fmaf(a.x, b.x, acc); acc = fmaf(a.y, b.y, acc);
            acc = fmaf(a.z, b.z, acc); acc = fmaf(a.w, b.w, acc);
        }
        acc += __shfl_xor(acc, 1);
        acc += __shfl_xor(acc, 2);
        acc += __shfl_xor(acc, 4);
    }

    // gather 8 exact scores, exact top-4
    float bv[4]; int bi[4];
    #pragma unroll
    for (int q = 0; q < 4; ++q) { bv[q] = NEG_INF_; bi[q] = INT_MAX; }
    #pragma unroll
    for (int g2 = 0; g2 < 8; ++g2) {
        float vg = __shfl(acc, g2 * 8);
        ins4tb(vg, candi[w][g2], bv, bi);
    }
    if (l == 0) {
        float4 fv; fv.x = bv[0]; fv.y = bv[1]; fv.z = bv[2]; fv.w = bv[3];
        int4   iv; iv.x = bi[0]; iv.y = bi[1]; iv.z = bi[2]; iv.w = bi[3];
        *(float4*)(rval + (size_t)n * 4) = fv;
        *(int4*)(ridx + (size_t)n * 4)   = iv;
    }
}

// ---------------------------------------------------------------------------
// Kernel C: 5-level bilinear scatter (per-pixel private 405 channels).
// ---------------------------------------------------------------------------
__global__ __launch_bounds__(256)
void scatter2_kernel(const float* __restrict__ rval, const int* __restrict__ ridx,
                     const float* __restrict__ dflow, float* __restrict__ out)
{
    const int n = blockIdx.x * blockDim.x + threadIdx.x;
    if (n >= N_) return;

    float4 fv = *(const float4*)(rval + (size_t)n * 4);
    int4   iv = *(const int4*)(ridx + (size_t)n * 4);
    const float v[4]  = {fv.x, fv.y, fv.z, fv.w};
    const int   id[4] = {iv.x, iv.y, iv.z, iv.w};

    const int   y0  = n / W_;
    const int   x0  = n - y0 * W_;
    const float df0 = dflow[n];
    const float df1 = dflow[N_ + n];
    float ccy[4], ccx[4], cr[4];
    #pragma unroll
    for (int k = 0; k < 4; ++k) {
        const int m  = id[k];
        const int y1 = m / W_;
        const int x1 = m - y1 * W_;
        cr[k]  = v[k] * 0.0625f;
        ccy[k] = (float)(y1 - y0) - df1;
        ccx[k] = (float)(x1 - x0) - df0;
    }

    float scale = 1.0f;
    for (int lvl = 0; lvl < LEVELS_; ++lvl) {
        float bins[WIN_ * WIN_];
        for (int jj = 0; jj < WIN_ * WIN_; ++jj) bins[jj] = 0.0f;
        #pragma unroll
        for (int k = 0; k < 4; ++k) {
            const float cy = ccy[k] * scale;
            const float cx = ccx[k] * scale;
            const float yf = floorf(cy), xf = floorf(cx);
            const float dy = cy - yf,    dx = cx - xf;
            const float cyv[4] = {yf, yf, yf + 1.0f, yf + 1.0f};
            const float cxv[4] = {xf, xf + 1.0f, xf, xf + 1.0f};
            const float wv[4]  = {(1.0f-dy)*(1.0f-dx), (1.0f-dy)*dx, dy*(1.0f-dx), dy*dx};
            #pragma unroll
            for (int c = 0; c < 4; ++c) {
                if (fabsf(cyv[c]) <= (float)SR_ && fabsf(cxv[c]) <= (float)SR_) {
                    const int iy = (int)cyv[c] + SR_;
                    const int ix = (int)cxv[c] + SR_;
                    bins[iy * WIN_ + ix] += wv[c] * cr[k];
                }
            }
        }
        const size_t obase = (size_t)lvl * (WIN_ * WIN_) * N_ + n;
        for (int jj = 0; jj < WIN_ * WIN_; ++jj)
            out[obase + (size_t)jj * N_] = bins[jj];
        scale *= 0.5f;
    }
}

// ===========================================================================
// Fallback path (round-2 proven fp32 kernels) if workspace is too small.
// ===========================================================================
#define TILE_   64
#define KC_     16
#define NT_     ((N_ + TILE_ - 1) / TILE_)

__global__ __launch_bounds__(256)
void knn_partial_kernel(const float* __restrict__ f1, const float* __restrict__ f2,
                        float* __restrict__ pval, int* __restrict__ pidx,
                        int mt_per_split)
{
    __shared__ float As[KC_][TILE_];
    __shared__ float Bs[KC_][TILE_];
    __shared__ float Ss[TILE_][TILE_ + 1];
    const int nb = blockIdx.x, split = blockIdx.y, n0 = nb * TILE_;
    const int tid = threadIdx.x, tx = tid & 15, ty = tid >> 4;
    const int lr = tid >> 4, lc = (tid & 15) * 4;
    const bool edge_n = (n0 + TILE_ > N_);
    float rv0 = NEG_INF_, rv1 = NEG_INF_, rv2 = NEG_INF_, rv3 = NEG_INF_;
    int ri0 = 0, ri1 = 0, ri2 = 0, ri3 = 0;
    const int mt_begin = split * mt_per_split;
    const int mt_end = (mt_begin + mt_per_split < NT_) ? (mt_begin + mt_per_split) : NT_;
    for (int mt = mt_begin; mt < mt_end; ++mt) {
        const int m0 = mt * TILE_;
        const bool edge_m = (m0 + TILE_ > N_);
        float acc[4][4];
        #pragma unroll
        for (int i = 0; i < 4; ++i) {
            #pragma unroll
            for (int j = 0; j < 4; ++j) acc[i][j] = 0.0f;
        }
        for (int kc = 0; kc < C_; kc += KC_) {
            __syncthreads();
            const float* a_src = f1 + (size_t)(kc + lr) * N_;
            const float* b_src = f2 + (size_t)(kc + lr) * N_;
            if (!edge_n) {
                *(float4*)&As[lr][lc] = *(const float4*)(a_src + n0 + lc);
            } else {
                for (int i = 0; i < 4; ++i) {
                    int n = n0 + lc + i; if (n > N_ - 1) n = N_ - 1;
                    As[lr][lc + i] = a_src[n];
                }
            }
            if (!edge_m) {
                *(float4*)&Bs[lr][lc] = *(const float4*)(b_src + m0 + lc);
            } else {
                for (int i = 0; i < 4; ++i) {
                    int m = m0 + lc + i; if (m > N_ - 1) m = N_ - 1;
                    Bs[lr][lc + i] = b_src[m];
                }
            }
            __syncthreads();
            #pragma unroll
            for (int k = 0; k < KC_; ++k) {
                const float4 a = *(const float4*)&As[k][ty * 4];
                const float4 b = *(const float4*)&Bs[k][tx * 4];
                acc[0][0]=fmaf(a.x,b.x,acc[0][0]); acc[0][1]=fmaf(a.x,b.y,acc[0][1]);
                acc[0][2]=fmaf(a.x,b.z,acc[0][2]); acc[0][3]=fmaf(a.x,b.w,acc[0][3]);
                acc[1][0]=fmaf(a.y,b.x,acc[1][0]); acc[1][1]=fmaf(a.y,b.y,acc[1][1]);
                acc[1][2]=fmaf(a.y,b.z,acc[1][2]); acc[1][3]=fmaf(a.y,b.w,acc[1][3]);
                acc[2][0]=fmaf(a.z,b.x,acc[2][0]); acc[2][1]=fmaf(a.z,b.y,acc[2][1]);
                acc[2][2]=fmaf(a.z,b.z,acc[2][2]); acc[2][3]=fmaf(a.z,b.w,acc[2][3]);
                acc[3][0]=fmaf(a.w,b.x,acc[3][0]); acc[3][1]=fmaf(a.w,b.y,acc[3][1]);
                acc[3][2]=fmaf(a.w,b.z,acc[3][2]); acc[3][3]=fmaf(a.w,b.w,acc[3][3]);
            }
        }
        __syncthreads();
        #pragma unroll
        for (int i = 0; i < 4; ++i) {
            #pragma unroll
            for (int j = 0; j < 4; ++j) Ss[ty*4+i][tx*4+j] = acc[i][j];
        }
        __syncthreads();
        if (tid < TILE_) {
            const int mlim = edge_m ? (N_ - m0) : TILE_;
            for (int m = 0; m < mlim; ++m) {
                const float sc = Ss[tid][m];
                if (sc > rv3) {
                    const int mi = m0 + m;
                    if (sc > rv1) {
                        if (sc > rv0) { rv3=rv2; ri3=ri2; rv2=rv1; ri2=ri1; rv1=rv0; ri1=ri0; rv0=sc; ri0=mi; }
                        else          { rv3=rv2; ri3=ri2; rv2=rv1; ri2=ri1; rv1=sc; ri1=mi; }
                    } else {
                        if (sc > rv2) { rv3=rv2; ri3=ri2; rv2=sc; ri2=mi; }
                        else          { rv3=sc; ri3=mi; }
                    }
                }
            }
        }
        __syncthreads();
    }
    if (tid < TILE_) {
        const int n = n0 + tid;
        if (n < N_) {
            const size_t base = ((size_t)split * N_ + n) * 4;
            pval[base+0]=rv0; pidx[base+0]=ri0; pval[base+1]=rv1; pidx[base+1]=ri1;
            pval[base+2]=rv2; pidx[base+2]=ri2; pval[base+3]=rv3; pidx[base+3]=ri3;
        }
    }
}

__global__ __launch_bounds__(256)
void scatter_kernel(const float* __restrict__ pval, const int* __restrict__ pidx,
                    const float* __restrict__ dflow, float* __restrict__ out, int splits)
{
    const int n = blockIdx.x * blockDim.x + threadIdx.x;
    if (n >= N_) return;
    float v[4] = {NEG_INF_, NEG_INF_, NEG_INF_, NEG_INF_};
    int id[4] = {0, 0, 0, 0};
    for (int sp = 0; sp < splits; ++sp) {
        const size_t base = ((size_t)sp * N_ + n) * 4;
        #pragma unroll
        for (int k = 0; k < 4; ++k) ins4tb(pval[base + k], pidx[base + k], v, id);
    }
    const int y0 = n / W_, x0 = n - y0 * W_;
    const float df0 = dflow[n], df1 = dflow[N_ + n];
    float ccy[4], ccx[4], cr[4];
    #pragma unroll
    for (int k = 0; k < 4; ++k) {
        const int m = id[k], y1 = m / W_, x1 = m - y1 * W_;
        cr[k] = v[k] * 0.0625f;
        ccy[k] = (float)(y1 - y0) - df1; ccx[k] = (float)(x1 - x0) - df0;
    }
    float scale = 1.0f;
    for (int lvl = 0; lvl < LEVELS_; ++lvl) {
        float bins[WIN_ * WIN_];
        for (int jj = 0; jj < WIN_ * WIN_; ++jj) bins[jj] = 0.0f;
        #pragma unroll
        for (int k = 0; k < 4; ++k) {
            const float cy = ccy[k] * scale, cx = ccx[k] * scale;
            const float yf = floorf(cy), xf = floorf(cx);
            const float dy = cy - yf, dx = cx - xf;
            const float cyv[4] = {yf, yf, yf + 1.0f, yf + 1.0f};
            const float cxv[4] = {xf, xf + 1.0f, xf, xf + 1.0f};
            const float wv[4] = {(1.0f-dy)*(1.0f-dx), (1.0f-dy)*dx, dy*(1.0f-dx), dy*dx};
            #pragma unroll
            for (int c = 0; c < 4; ++c) {
                if (fabsf(cyv[c]) <= (float)SR_ && fabsf(cxv[c]) <= (float)SR_) {
                    bins[((int)cyv[c] + SR_) * WIN_ + (int)cxv[c] + SR_] += wv[c] * cr[k];
                }
            }
        }
        const size_t obase = (size_t)lvl * (WIN_ * WIN_) * N_ + n;
        for (int jj = 0; jj < WIN_ * WIN_; ++jj) out[obase + (size_t)jj * N_] = bins[jj];
        scale *= 0.5f;
    }
}

// ---------------------------------------------------------------------------
extern "C" void kernel_launch(void* const* d_in, const int* in_sizes, int n_in,
                              void* d_out, int out_size, void* d_ws, size_t ws_size,
                              hipStream_t stream)
{
    const float* f1    = (const float*)d_in[0];
    const float* f2    = (const float*)d_in[1];
    const float* dflow = (const float*)d_in[2];
    float*       out   = (float*)d_out;

    // ---- MFMA path workspace layout ----
    const size_t NC2   = (size_t)N_ * C_ * 2;           // bf16 plane bytes
    const size_t o_f2hi = 0;
    const size_t o_f2lo = NC2;
    const size_t o_f1hi = 2 * NC2;
    const size_t o_f1lo = 3 * NC2;
    const size_t o_f1T  = 4 * NC2;                      // fp32 = 2*NC2 bytes
    const size_t o_f2T  = 6 * NC2;
    const size_t o_pval = 8 * NC2;
    const size_t sz_p   = (size_t)SPL_ * N_ * 4 * 4;
    const size_t o_pidx = o_pval + sz_p;
    const size_t o_rval = o_pidx + sz_p;
    const size_t sz_r   = (size_t)N_ * 4 * 4;
    const size_t o_ridx = o_rval + sz_r;
    const size_t total  = o_ridx + sz_r;

    if (ws_size >= total) {
        char* ws = (char*)d_ws;
        unsigned short* f2hi = (unsigned short*)(ws + o_f2hi);
        unsigned short* f2lo = (unsigned short*)(ws + o_f2lo);
        unsigned short* f1hi = (unsigned short*)(ws + o_f1hi);
        unsigned short* f1lo = (unsigned short*)(ws + o_f1lo);
        float* f1T  = (float*)(ws + o_f1T);
        float* f2T  = (float*)(ws + o_f2T);
        float* pval = (float*)(ws + o_pval);
        int*   pidx = (int*)(ws + o_pidx);
        float* rval = (float*)(ws + o_rval);
        int*   ridx = (int*)(ws + o_ridx);

        dim3 gp(C_ / 64, (N_ + 63) / 64, 2);
        prep_kernel<<<gp, 256, 0, stream>>>(f1, f2, f1hi, f1lo, f2hi, f2lo, f1T, f2T);

        dim3 ga(NTB_, SPL_);
        knn_mfma_kernel<<<ga, 256, 0, stream>>>(f1hi, f1lo, f2hi, f2lo, pval, pidx);

        rescore_kernel<<<(N_ + 3) / 4, 256, 0, stream>>>(pval, pidx, f1T, f2T, rval, ridx);

        scatter2_kernel<<<(N_ + 255) / 256, 256, 0, stream>>>(rval, ridx, dflow, out);
    } else {
        // fallback: round-2 fp32 path
        const size_t per_split = (size_t)N_ * 32u;
        int splits = 1;
        while (splits < 8 && (size_t)(splits * 2) * per_split <= ws_size) splits *= 2;
        float* pval = (float*)d_ws;
        int*   pidx = (int*)((char*)d_ws + (size_t)splits * N_ * 4 * sizeof(float));
        const int mps = (NT_ + splits - 1) / splits;
        dim3 gridA(NT_, splits);
        knn_partial_kernel<<<gridA, 256, 0, stream>>>(f1, f2, pval, pidx, mps);
        scatter_kernel<<<(N_ + 255) / 256, 256, 0, stream>>>(pval, pidx, dflow, out, splits);
    }
}